// Round 15
// baseline (286.825 us; speedup 1.0000x reference)
//
#include <hip/hip_runtime.h>

// Fused grouped 4-layer MLP: 64 models × 32768 tokens, d=64, fp32 in/out.
//
// R15 = R13's pipeline at 2x TLP: 1024-thread blocks (16 waves) sharing ONE
// 32KB W image. LDS = 32K W + 16 x 2 x 4KB bufs = 163840 (160 KiB exact) ->
// 1 block/CU = 16 waves/CU (was 8 since R4). Grid 256 = exactly one round
// (R14's regression config was 2 rounds of 1-block/CU; this avoids it).
// The ~1000-cyc serial compute chain per tile (cvt->4x[MFMA->repack]->bounce)
// is latency only MORE WAVES can hide - load-depth (R14) is exhausted.
//
// Depth-2 with only DUAL buffers: issue D(s+2) into bufc AFTER the bounce
// reads (bufc free then; still ~1 iteration ahead of use). Per-iter op order:
// [stores S(s), DMA D(s+2)] -> steady wait vmcnt(8) = require D(s+1) only
// (also retires S(s-1), ~6us old, harmless). Prologue D0,D1 -> vmcnt(4).
//
// Contiguity (R11): loads global_load_lds dwordx4 NT (1KB contiguous/instr,
// pre-swizzled per-lane SOURCE, linear LDS dest) -> ds_read_b128 at
// S=(c*256+t*64+g*16)^((c&7)<<4) conflict-free; stores bounce ds_write(S) ->
// ds_read(linear^swz) -> contiguous NT global_store_dwordx4. Wave-private
// bufs, no barriers after W staging. Bias packed-bf16 in regs. MFMA
// D[f][tok]; k-map k=32kk+16(j>>2)+4g+(j&3) both operands; C/D col=lane&15,
// row=4*(lane>>4)+reg.

typedef __attribute__((ext_vector_type(8))) _Float16 f16x8;
typedef __attribute__((ext_vector_type(2))) __fp16 fp16x2;
typedef __attribute__((ext_vector_type(4))) float f32x4;

#define MODELS 64
#define LAYERS 4
#define DIM 64
#define TOKS_PER_MODEL 32768
#define THREADS 1024
#define WAVES_PER_BLOCK 16
#define BLOCKS_PER_MODEL 4
#define WAVES_PER_MODEL 64
#define STEPS 32
#define STEP_FLOATS ((size_t)WAVES_PER_MODEL * 16 * DIM)   // 65536 floats
#define STEP_BYTES (STEP_FLOATS * 4)                        // 262144 B
#define NBUF 2

#define WF_BYTES (LAYERS * 4 * 2 * 64 * 16)   // 32768
#define XBUF_OFF WF_BYTES
#define LDS_BYTES (WF_BYTES + WAVES_PER_BLOCK * NBUF * 4096)  // 163840 = 160 KiB

union H8 { f16x8 v; fp16x2 h2[4]; };

static __device__ __forceinline__ unsigned bf16bits(float f) {
    unsigned u = __builtin_bit_cast(unsigned, f);
    return (u + 0x7fffu + ((u >> 16) & 1u)) >> 16; // RNE
}

// NT streaming DMA: global -> LDS, 16B/lane.
static __device__ __forceinline__ void dma16(const void* g, void* l) {
    __builtin_amdgcn_global_load_lds(
        (const __attribute__((address_space(1))) unsigned int*)g,
        (__attribute__((address_space(3))) unsigned int*)l, 16, 0, 2);
}

#define CVT_Z(Z0, Z1, X0, X1, X2, X3)                              \
    {                                                              \
        H8 z0u_, z1u_;                                             \
        z0u_.h2[0] = __builtin_amdgcn_cvt_pkrtz(X0[0], X0[1]);     \
        z0u_.h2[1] = __builtin_amdgcn_cvt_pkrtz(X0[2], X0[3]);     \
        z0u_.h2[2] = __builtin_amdgcn_cvt_pkrtz(X1[0], X1[1]);     \
        z0u_.h2[3] = __builtin_amdgcn_cvt_pkrtz(X1[2], X1[3]);     \
        z1u_.h2[0] = __builtin_amdgcn_cvt_pkrtz(X2[0], X2[1]);     \
        z1u_.h2[1] = __builtin_amdgcn_cvt_pkrtz(X2[2], X2[3]);     \
        z1u_.h2[2] = __builtin_amdgcn_cvt_pkrtz(X3[0], X3[1]);     \
        z1u_.h2[3] = __builtin_amdgcn_cvt_pkrtz(X3[2], X3[3]);     \
        Z0 = z0u_.v; Z1 = z1u_.v;                                  \
    }

__global__ __launch_bounds__(THREADS) void mlp4_fused(
    const float* __restrict__ x, const float* __restrict__ W,
    const float* __restrict__ b, float* __restrict__ out) {

    __shared__ __align__(16) unsigned char smem[LDS_BYTES];

    const int lane = threadIdx.x & 63;
    const int wave = threadIdx.x >> 6;          // 0..15
    const int c = lane & 15;   // token col (B/D) and W feature row (A)
    const int g = lane >> 4;   // k-group

    const int m   = blockIdx.x / BLOCKS_PER_MODEL;
    const int blk = blockIdx.x % BLOCKS_PER_MODEL;
    const int q   = blk * WAVES_PER_BLOCK + wave;   // wave slot in model, 0..63

    // ---- staging: wave w stages layer (w>>2), t = w&3 (16 waves = 16 pairs) ----
    {
        const int l = wave >> 2;
        const int t = wave & 3;
        const float* Wl = W + ((size_t)m * LAYERS + l) * DIM * DIM;
        const float* row = Wl + (size_t)(t * 16 + c) * DIM + 4 * g;
        f32x4 c0 = *(const f32x4*)(row + 0);
        f32x4 c1 = *(const f32x4*)(row + 16);
        f32x4 c2 = *(const f32x4*)(row + 32);
        f32x4 c3 = *(const f32x4*)(row + 48);
        H8 a0, a1;
        #pragma unroll
        for (int e = 0; e < 4; ++e) {
            a0.v[e]     = (_Float16)c0[e];
            a0.v[4 + e] = (_Float16)c1[e];
            a1.v[e]     = (_Float16)c2[e];
            a1.v[4 + e] = (_Float16)c3[e];
        }
        *(f16x8*)(smem + ((size_t)((l * 4 + t) * 2 + 0) * 1024) + lane * 16) = a0.v;
        *(f16x8*)(smem + ((size_t)((l * 4 + t) * 2 + 1) * 1024) + lane * 16) = a1.v;
    }

    // ---- bias in registers, packed 2×bf16 ----
    unsigned bpk[LAYERS][8];
    {
        const float* bm = b + (size_t)m * LAYERS * DIM;
        #pragma unroll
        for (int l = 0; l < LAYERS; ++l)
            #pragma unroll
            for (int t = 0; t < 4; ++t)
                #pragma unroll
                for (int p2 = 0; p2 < 2; ++p2) {
                    unsigned r0 = bf16bits(bm[l * DIM + t * 16 + 4 * g + 2 * p2]);
                    unsigned r1 = bf16bits(bm[l * DIM + t * 16 + 4 * g + 2 * p2 + 1]);
                    bpk[l][t * 2 + p2] = (r1 << 16) | r0;
                }
    }
    __syncthreads();

    // ---- per-lane offsets (R11-verified) ----
    int frOff[4];
    #pragma unroll
    for (int t = 0; t < 4; ++t)
        frOff[t] = (c * 256 + t * 64 + g * 16) ^ ((c & 7) << 4);

    int srcOff[4], brOff[4];
    #pragma unroll
    for (int kk = 0; kk < 4; ++kk) {
        const int cc = kk * 4 + (lane >> 4);
        const int u  = lane & 15;
        const int v  = (u & 8) | ((u & 7) ^ (cc & 7));
        srcOff[kk] = cc * 256 + (v >> 2) * 64 + (v & 3) * 16;
        brOff[kk]  = (kk * 1024 + lane * 16) ^ ((cc & 7) << 4);
    }

    const char* xTile = (const char*)(x + ((size_t)m * TOKS_PER_MODEL + (size_t)q * 16) * DIM);
    char*       oBase = (char*)(out + ((size_t)m * TOKS_PER_MODEL + (size_t)q * 16) * DIM) + lane * 16;
    unsigned char* xb = smem + XBUF_OFF + wave * (NBUF * 4096);  // two 4 KB bufs

    // prologue: DMA tile 0 -> b0, tile 1 -> b1; wait tile 0 (D1 stays in flight)
    #pragma unroll
    for (int kk = 0; kk < 4; ++kk)
        dma16(xTile + srcOff[kk], xb + kk * 1024);
    #pragma unroll
    for (int kk = 0; kk < 4; ++kk)
        dma16(xTile + STEP_BYTES + srcOff[kk], xb + 4096 + kk * 1024);
    asm volatile("s_waitcnt vmcnt(4)" ::: "memory");

    #pragma unroll 1
    for (int s = 0; s < STEPS; ++s) {
        unsigned char* bufc = xb + (s & 1) * 4096;

        // x fragments from LDS (conflict-free swizzled b128)
        f32x4 X0 = *(const f32x4*)(bufc + frOff[0]);
        f32x4 X1 = *(const f32x4*)(bufc + frOff[1]);
        f32x4 X2 = *(const f32x4*)(bufc + frOff[2]);
        f32x4 X3 = *(const f32x4*)(bufc + frOff[3]);

        f16x8 z0, z1;
        CVT_Z(z0, z1, X0, X1, X2, X3);

        f32x4 acc[4];
        #pragma unroll
        for (int l = 0; l < LAYERS; ++l) {
            #pragma unroll
            for (int t = 0; t < 4; ++t) {
                unsigned p0 = bpk[l][t * 2], p1 = bpk[l][t * 2 + 1];
                acc[t][0] = __builtin_bit_cast(float, p0 << 16);
                acc[t][1] = __builtin_bit_cast(float, p0 & 0xffff0000u);
                acc[t][2] = __builtin_bit_cast(float, p1 << 16);
                acc[t][3] = __builtin_bit_cast(float, p1 & 0xffff0000u);
            }
            #pragma unroll
            for (int t = 0; t < 4; ++t) {
                f16x8 w0 = *(const f16x8*)(smem + ((size_t)((l * 4 + t) * 2 + 0) * 1024) + lane * 16);
                acc[t] = __builtin_amdgcn_mfma_f32_16x16x32_f16(w0, z0, acc[t], 0, 0, 0);
            }
            #pragma unroll
            for (int t = 0; t < 4; ++t) {
                f16x8 w1 = *(const f16x8*)(smem + ((size_t)((l * 4 + t) * 2 + 1) * 1024) + lane * 16);
                acc[t] = __builtin_amdgcn_mfma_f32_16x16x32_f16(w1, z1, acc[t], 0, 0, 0);
            }
            if (l < LAYERS - 1) {
                H8 n0, n1;
                #pragma unroll
                for (int t = 0; t < 2; ++t) {
                    n0.h2[t * 2 + 0] = __builtin_amdgcn_cvt_pkrtz(
                        fmaxf(acc[t][0], 0.0f), fmaxf(acc[t][1], 0.0f));
                    n0.h2[t * 2 + 1] = __builtin_amdgcn_cvt_pkrtz(
                        fmaxf(acc[t][2], 0.0f), fmaxf(acc[t][3], 0.0f));
                    n1.h2[t * 2 + 0] = __builtin_amdgcn_cvt_pkrtz(
                        fmaxf(acc[2 + t][0], 0.0f), fmaxf(acc[2 + t][1], 0.0f));
                    n1.h2[t * 2 + 1] = __builtin_amdgcn_cvt_pkrtz(
                        fmaxf(acc[2 + t][2], 0.0f), fmaxf(acc[2 + t][3], 0.0f));
                }
                z0 = n0.v;
                z1 = n1.v;
            }
        }

        // out bounce through bufc (tile s fully consumed into z regs at CVT)
        #pragma unroll
        for (int t = 0; t < 4; ++t) {
            f32x4 res;
            #pragma unroll
            for (int r = 0; r < 4; ++r) res[r] = fmaxf(acc[t][r], 0.0f);
            *(f32x4*)(bufc + frOff[t]) = res;            // ds_write_b128, swizzled
        }
        asm volatile("s_waitcnt lgkmcnt(0)" ::: "memory");
        __builtin_amdgcn_sched_barrier(0);

        {
            char* o = oBase + (size_t)s * STEP_BYTES;
            f32x4 O0 = *(const f32x4*)(bufc + brOff[0]);
            f32x4 O1 = *(const f32x4*)(bufc + brOff[1]);
            f32x4 O2 = *(const f32x4*)(bufc + brOff[2]);
            f32x4 O3 = *(const f32x4*)(bufc + brOff[3]);
            __builtin_nontemporal_store(O0, (f32x4*)(o + 0));     // contiguous 1 KB, NT
            __builtin_nontemporal_store(O1, (f32x4*)(o + 1024));
            __builtin_nontemporal_store(O2, (f32x4*)(o + 2048));
            __builtin_nontemporal_store(O3, (f32x4*)(o + 3072));
        }

        // NOW bufc is free (bounce reads done): issue DMA for tile s+2 into it.
        // Still ~1 full iteration ahead of its consumption at iter s+2.
        {
            const int tn = (s + 2 < STEPS) ? (s + 2) : (STEPS - 1); // clamp tail
            const size_t ns = (size_t)tn * STEP_BYTES;
            #pragma unroll
            for (int kk = 0; kk < 4; ++kk)
                dma16(xTile + ns + srcOff[kk], bufc + kk * 1024);
        }

        // counted wait: outstanding [S(s-1)?, D(s+1), S(s), D(s+2)];
        // vmcnt(8) requires D(s+1) (and S(s-1), ~6us old) retired only.
        asm volatile("s_waitcnt vmcnt(8)" ::: "memory");
    }
}

extern "C" void kernel_launch(void* const* d_in, const int* in_sizes, int n_in,
                              void* d_out, int out_size, void* d_ws, size_t ws_size,
                              hipStream_t stream) {
    (void)in_sizes; (void)n_in; (void)out_size; (void)d_ws; (void)ws_size;
    const float* x = (const float*)d_in[0];
    const float* W = (const float*)d_in[1];
    const float* b = (const float*)d_in[2];
    float* out = (float*)d_out;
    mlp4_fused<<<dim3(MODELS * BLOCKS_PER_MODEL), dim3(THREADS), 0, stream>>>(x, W, b, out);
}

// Round 16
// 210.589 us; speedup vs baseline: 1.3620x; 1.3620x over previous
//
#include <hip/hip_runtime.h>

// Fused grouped 4-layer MLP: 64 models × 32768 tokens, d=64, fp32 in/out.
//
// R16 = R13 (best: 208 us) + two refinements, geometry untouched:
//  (1) ONE resident round: grid 512 (8 blocks/model, 4-wave blocks, q 0..31,
//      STEPS=64). R13's grid 1024 at 2 blocks/CU = 512 slots ran 2 rounds ->
//      2x W-staging + fill/drain + straggler tail. 80KB LDS, 2 blocks/CU.
//  (2) drop the forced lgkmcnt(0)+sched_barrier between bounce ds_write and
//      ds_read: per-wave LDS ops process IN ORDER (same-addr RAW safe); the
//      hard drain was pure serialization. Compiler still waits before the
//      global stores consume the read data.
// R14/R15 lesson: depth-3 and 16-wave/1-block-per-CU both regress hard;
// R13's 4-wave x 2-block geometry + depth-2 + counted-wait + NT is the
// winning structure.
//
// Pipeline (per wave, wave-private bufs, no barriers after staging):
//   iter s: ds_read x-frags from buf s%3 -> issue NT DMA(tile s+2) into
//   buf (s+2)%3 -> cvt -> 4-layer MFMA chain -> bounce ds_write/ds_read ->
//   contiguous NT stores -> vmcnt(12) (= require D(s+1) only; stores float).
// Contiguity (R11): global_load_lds dwordx4 (1KB contiguous/instr,
// pre-swizzled per-lane SOURCE, linear LDS dest); frag reads at
// S=(c*256+t*64+g*16)^((c&7)<<4) conflict-free; stores bounced to contiguous.
// Bias packed-bf16 in regs. MFMA D[f][tok]; k-map k=32kk+16(j>>2)+4g+(j&3)
// both operands; C/D col=lane&15, row=4*(lane>>4)+reg.

typedef __attribute__((ext_vector_type(8))) _Float16 f16x8;
typedef __attribute__((ext_vector_type(2))) __fp16 fp16x2;
typedef __attribute__((ext_vector_type(4))) float f32x4;

#define MODELS 64
#define LAYERS 4
#define DIM 64
#define TOKS_PER_MODEL 32768
#define BLOCKS_PER_MODEL 8
#define WAVES_PER_BLOCK 4
#define WAVES_PER_MODEL (BLOCKS_PER_MODEL * WAVES_PER_BLOCK)   // 32
#define STEPS (TOKS_PER_MODEL / (WAVES_PER_MODEL * 16))        // 64
#define STEP_FLOATS ((size_t)WAVES_PER_MODEL * 16 * DIM)       // 32768 floats
#define STEP_BYTES (STEP_FLOATS * 4)                            // 131072 B

#define WF_BYTES (LAYERS * 4 * 2 * 64 * 16)   // 32768
#define XBUF_OFF WF_BYTES                      // 4 waves × 3 bufs × 4096
#define LDS_BYTES (WF_BYTES + WAVES_PER_BLOCK * 3 * 4096)  // 81920 -> 2 blocks/CU

union H8 { f16x8 v; fp16x2 h2[4]; };

static __device__ __forceinline__ unsigned bf16bits(float f) {
    unsigned u = __builtin_bit_cast(unsigned, f);
    return (u + 0x7fffu + ((u >> 16) & 1u)) >> 16; // RNE
}

// NT streaming DMA: global -> LDS, 16B/lane.
static __device__ __forceinline__ void dma16(const void* g, void* l) {
    __builtin_amdgcn_global_load_lds(
        (const __attribute__((address_space(1))) unsigned int*)g,
        (__attribute__((address_space(3))) unsigned int*)l, 16, 0, 2);
}

#define CVT_Z(Z0, Z1, X0, X1, X2, X3)                              \
    {                                                              \
        H8 z0u_, z1u_;                                             \
        z0u_.h2[0] = __builtin_amdgcn_cvt_pkrtz(X0[0], X0[1]);     \
        z0u_.h2[1] = __builtin_amdgcn_cvt_pkrtz(X0[2], X0[3]);     \
        z0u_.h2[2] = __builtin_amdgcn_cvt_pkrtz(X1[0], X1[1]);     \
        z0u_.h2[3] = __builtin_amdgcn_cvt_pkrtz(X1[2], X1[3]);     \
        z1u_.h2[0] = __builtin_amdgcn_cvt_pkrtz(X2[0], X2[1]);     \
        z1u_.h2[1] = __builtin_amdgcn_cvt_pkrtz(X2[2], X2[3]);     \
        z1u_.h2[2] = __builtin_amdgcn_cvt_pkrtz(X3[0], X3[1]);     \
        z1u_.h2[3] = __builtin_amdgcn_cvt_pkrtz(X3[2], X3[3]);     \
        Z0 = z0u_.v; Z1 = z1u_.v;                                  \
    }

__global__ __launch_bounds__(256, 2) void mlp4_fused(
    const float* __restrict__ x, const float* __restrict__ W,
    const float* __restrict__ b, float* __restrict__ out) {

    __shared__ __align__(16) unsigned char smem[LDS_BYTES];

    const int lane = threadIdx.x & 63;
    const int wave = threadIdx.x >> 6;
    const int c = lane & 15;   // token col (B/D) and W feature row (A)
    const int g = lane >> 4;   // k-group

    const int m   = blockIdx.x / BLOCKS_PER_MODEL;
    const int blk = blockIdx.x % BLOCKS_PER_MODEL;
    const int q   = blk * WAVES_PER_BLOCK + wave;   // wave slot in model, 0..31

    // ---- stage this wave's layer (l = wave) of W into LDS ----
    {
        const int l = wave;
        const float* Wl = W + ((size_t)m * LAYERS + l) * DIM * DIM;
        #pragma unroll
        for (int t = 0; t < 4; ++t) {
            const float* row = Wl + (size_t)(t * 16 + c) * DIM + 4 * g;
            f32x4 c0 = *(const f32x4*)(row + 0);
            f32x4 c1 = *(const f32x4*)(row + 16);
            f32x4 c2 = *(const f32x4*)(row + 32);
            f32x4 c3 = *(const f32x4*)(row + 48);
            H8 a0, a1;
            #pragma unroll
            for (int e = 0; e < 4; ++e) {
                a0.v[e]     = (_Float16)c0[e];
                a0.v[4 + e] = (_Float16)c1[e];
                a1.v[e]     = (_Float16)c2[e];
                a1.v[4 + e] = (_Float16)c3[e];
            }
            *(f16x8*)(smem + ((size_t)((l * 4 + t) * 2 + 0) * 1024) + lane * 16) = a0.v;
            *(f16x8*)(smem + ((size_t)((l * 4 + t) * 2 + 1) * 1024) + lane * 16) = a1.v;
        }
    }

    // ---- bias in registers, packed 2×bf16 ----
    unsigned bpk[LAYERS][8];
    {
        const float* bm = b + (size_t)m * LAYERS * DIM;
        #pragma unroll
        for (int l = 0; l < LAYERS; ++l)
            #pragma unroll
            for (int t = 0; t < 4; ++t)
                #pragma unroll
                for (int p2 = 0; p2 < 2; ++p2) {
                    unsigned r0 = bf16bits(bm[l * DIM + t * 16 + 4 * g + 2 * p2]);
                    unsigned r1 = bf16bits(bm[l * DIM + t * 16 + 4 * g + 2 * p2 + 1]);
                    bpk[l][t * 2 + p2] = (r1 << 16) | r0;
                }
    }
    __syncthreads();

    // ---- per-lane offsets (R11-verified) ----
    int frOff[4];
    #pragma unroll
    for (int t = 0; t < 4; ++t)
        frOff[t] = (c * 256 + t * 64 + g * 16) ^ ((c & 7) << 4);

    int srcOff[4], brOff[4];
    #pragma unroll
    for (int kk = 0; kk < 4; ++kk) {
        const int cc = kk * 4 + (lane >> 4);
        const int u  = lane & 15;
        const int v  = (u & 8) | ((u & 7) ^ (cc & 7));
        srcOff[kk] = cc * 256 + (v >> 2) * 64 + (v & 3) * 16;
        brOff[kk]  = (kk * 1024 + lane * 16) ^ ((cc & 7) << 4);
    }

    const char* xTile = (const char*)(x + ((size_t)m * TOKS_PER_MODEL + (size_t)q * 16) * DIM);
    char*       oBase = (char*)(out + ((size_t)m * TOKS_PER_MODEL + (size_t)q * 16) * DIM) + lane * 16;
    unsigned char* xb = smem + XBUF_OFF + wave * (3 * 4096);  // three 4 KB bufs

    // prologue: DMA tile 0 -> b0, tile 1 -> b1; wait tile 0 only
    #pragma unroll
    for (int kk = 0; kk < 4; ++kk)
        dma16(xTile + srcOff[kk], xb + kk * 1024);
    #pragma unroll
    for (int kk = 0; kk < 4; ++kk)
        dma16(xTile + STEP_BYTES + srcOff[kk], xb + 4096 + kk * 1024);
    asm volatile("s_waitcnt vmcnt(4)" ::: "memory");

    int p = 0;
    #pragma unroll 1
    for (int s = 0; s < STEPS; ++s) {
        unsigned char* bufc = xb + p * 4096;

        // x fragments from LDS (conflict-free swizzled b128)
        f32x4 X0 = *(const f32x4*)(bufc + frOff[0]);
        f32x4 X1 = *(const f32x4*)(bufc + frOff[1]);
        f32x4 X2 = *(const f32x4*)(bufc + frOff[2]);
        f32x4 X3 = *(const f32x4*)(bufc + frOff[3]);

        // issue DMA for tile s+2 into buf (p+2)%3 (holds tile s-1: consumed)
        {
            int pd = p + 2; if (pd >= 3) pd -= 3;
            const int tn = (s + 2 < STEPS) ? (s + 2) : (STEPS - 1); // clamp tail
            const size_t ns = (size_t)tn * STEP_BYTES;
            unsigned char* nb = xb + pd * 4096;
            #pragma unroll
            for (int kk = 0; kk < 4; ++kk)
                dma16(xTile + ns + srcOff[kk], nb + kk * 1024);
        }

        f16x8 z0, z1;
        CVT_Z(z0, z1, X0, X1, X2, X3);

        f32x4 acc[4];
        #pragma unroll
        for (int l = 0; l < LAYERS; ++l) {
            #pragma unroll
            for (int t = 0; t < 4; ++t) {
                unsigned p0 = bpk[l][t * 2], p1 = bpk[l][t * 2 + 1];
                acc[t][0] = __builtin_bit_cast(float, p0 << 16);
                acc[t][1] = __builtin_bit_cast(float, p0 & 0xffff0000u);
                acc[t][2] = __builtin_bit_cast(float, p1 << 16);
                acc[t][3] = __builtin_bit_cast(float, p1 & 0xffff0000u);
            }
            #pragma unroll
            for (int t = 0; t < 4; ++t) {
                f16x8 w0 = *(const f16x8*)(smem + ((size_t)((l * 4 + t) * 2 + 0) * 1024) + lane * 16);
                acc[t] = __builtin_amdgcn_mfma_f32_16x16x32_f16(w0, z0, acc[t], 0, 0, 0);
            }
            #pragma unroll
            for (int t = 0; t < 4; ++t) {
                f16x8 w1 = *(const f16x8*)(smem + ((size_t)((l * 4 + t) * 2 + 1) * 1024) + lane * 16);
                acc[t] = __builtin_amdgcn_mfma_f32_16x16x32_f16(w1, z1, acc[t], 0, 0, 0);
            }
            if (l < LAYERS - 1) {
                H8 n0, n1;
                #pragma unroll
                for (int t = 0; t < 2; ++t) {
                    n0.h2[t * 2 + 0] = __builtin_amdgcn_cvt_pkrtz(
                        fmaxf(acc[t][0], 0.0f), fmaxf(acc[t][1], 0.0f));
                    n0.h2[t * 2 + 1] = __builtin_amdgcn_cvt_pkrtz(
                        fmaxf(acc[t][2], 0.0f), fmaxf(acc[t][3], 0.0f));
                    n1.h2[t * 2 + 0] = __builtin_amdgcn_cvt_pkrtz(
                        fmaxf(acc[2 + t][0], 0.0f), fmaxf(acc[2 + t][1], 0.0f));
                    n1.h2[t * 2 + 1] = __builtin_amdgcn_cvt_pkrtz(
                        fmaxf(acc[2 + t][2], 0.0f), fmaxf(acc[2 + t][3], 0.0f));
                }
                z0 = n0.v;
                z1 = n1.v;
            }
        }

        // out bounce through bufc: ds_write(S) -> ds_read(linear^swz).
        // Per-wave LDS ops are processed in order -> same-addr RAW safe with
        // NO explicit lgkm drain (compiler waits before stores use the data).
        #pragma unroll
        for (int t = 0; t < 4; ++t) {
            f32x4 res;
            #pragma unroll
            for (int r = 0; r < 4; ++r) res[r] = fmaxf(acc[t][r], 0.0f);
            *(f32x4*)(bufc + frOff[t]) = res;            // ds_write_b128, swizzled
        }

        {
            char* o = oBase + (size_t)s * STEP_BYTES;
            f32x4 O0 = *(const f32x4*)(bufc + brOff[0]);
            f32x4 O1 = *(const f32x4*)(bufc + brOff[1]);
            f32x4 O2 = *(const f32x4*)(bufc + brOff[2]);
            f32x4 O3 = *(const f32x4*)(bufc + brOff[3]);
            __builtin_nontemporal_store(O0, (f32x4*)(o + 0));     // contiguous 1 KB, NT
            __builtin_nontemporal_store(O1, (f32x4*)(o + 1024));
            __builtin_nontemporal_store(O2, (f32x4*)(o + 2048));
            __builtin_nontemporal_store(O3, (f32x4*)(o + 3072));
        }

        // counted wait: require ONLY tile s+1's DMA (all but newest 12 done);
        // prev-iter stores stay in flight. Iter 0's window is 8.
        if (s == 0) asm volatile("s_waitcnt vmcnt(8)"  ::: "memory");
        else        asm volatile("s_waitcnt vmcnt(12)" ::: "memory");
        p = (p + 1 == 3) ? 0 : p + 1;
    }
}

extern "C" void kernel_launch(void* const* d_in, const int* in_sizes, int n_in,
                              void* d_out, int out_size, void* d_ws, size_t ws_size,
                              hipStream_t stream) {
    (void)in_sizes; (void)n_in; (void)out_size; (void)d_ws; (void)ws_size;
    const float* x = (const float*)d_in[0];
    const float* W = (const float*)d_in[1];
    const float* b = (const float*)d_in[2];
    float* out = (float*)d_out;
    mlp4_fused<<<dim3(MODELS * BLOCKS_PER_MODEL), dim3(256), 0, stream>>>(x, W, b, out);
}